// Round 1
// baseline (377.982 us; speedup 1.0000x reference)
//
#include <hip/hip_runtime.h>

#define N_NODES 32768
#define N_EDGES 65536

typedef float f32x4 __attribute__((ext_vector_type(4)));
typedef short s16x8 __attribute__((ext_vector_type(8)));

__device__ __forceinline__ unsigned short f2bf(float f){
  unsigned u = __float_as_uint(f);
  u += 0x7FFFu + ((u >> 16) & 1u);          // round-to-nearest-even
  return (unsigned short)(u >> 16);
}
__device__ __forceinline__ float bf2f(unsigned short b){
  return __uint_as_float(((unsigned)b) << 16);
}

// ---------------- zero workspace (agg | cnt | pool contiguous) ----------------
__global__ void k_zero(float* __restrict__ p, int n){
  int i = blockIdx.x * 256 + threadIdx.x;
  if (i < n) p[i] = 0.f;
}

// ---------------- prep: W2t[kf][o][i] (129 slabs, slab 128 = e2_b2), T1x[o][288] ----------------
__global__ void k_prep(const float* __restrict__ e2_w2, const float* __restrict__ e2_b2,
                       const float* __restrict__ e1_w2, const float* __restrict__ e1_b2,
                       unsigned short* __restrict__ W2t, unsigned short* __restrict__ T1x){
  int idx = blockIdx.x * 256 + threadIdx.x;
  if (idx < 129 * 4096){
    int kf = idx >> 12, o = (idx >> 6) & 63, i = idx & 63;
    float v = (kf < 128) ? e2_w2[kf * 4096 + i * 64 + o] : e2_b2[i * 64 + o];
    W2t[idx] = f2bf(v);
  } else {
    int j = idx - 129 * 4096;
    if (j < 64 * 288){
      int o = j / 288, c = j % 288;
      float v = 0.f;
      if (c < 256)       v = e1_w2[(c >> 2) * 256 + (c & 3) * 64 + o];
      else if (c < 260)  v = e1_b2[(c - 256) * 64 + o];
      T1x[j] = f2bf(v);
    }
  }
}

// ---------------- degree counts ----------------
__global__ void k_cnt(const int* __restrict__ ei, float* __restrict__ cnt){
  int i = blockIdx.x * 256 + threadIdx.x;
  if (i < N_EDGES) atomicAdd(cnt + ei[N_EDGES + i], 1.f);
}

// ---------------- layer-1 edge messages: U1-GEMM (K=288 incl bias fold), MFMA ----------------
__launch_bounds__(128, 2)
__global__ void k_msg1(const float* __restrict__ x, const float* __restrict__ ea,
                       const int* __restrict__ ei,
                       const float* __restrict__ e1_w1, const float* __restrict__ e1_b1,
                       const unsigned short* __restrict__ T1xg,
                       float* __restrict__ agg)
{
  __shared__ unsigned short T1s[64 * 320];   // swizzled, padded row 320
  __shared__ unsigned short F1s[128 * 66];   // [edge][kf], padded
  __shared__ float eas[128 * 4];
  const int tid = threadIdx.x;
  const int eblk = blockIdx.x * 128;

  ((float4*)eas)[tid] = ((const float4*)ea)[eblk + tid];
  { // stage T1x with XOR swizzle
    int o = tid >> 1;
    int cb = (tid & 1) * 144;
    #pragma unroll
    for (int k = 0; k < 18; ++k){
      int c = cb + k * 8;
      s16x8 v = *(const s16x8*)(T1xg + o * 288 + c);
      *(s16x8*)&T1s[o * 320 + (c ^ ((o & 7) << 3))] = v;
    }
  }
  __syncthreads();
  { // F1 = relu(ea @ e1_w1 + b1), bf16
    int kf = tid & 63, eh = tid >> 6;
    float w0 = e1_w1[kf], w1 = e1_w1[64 + kf], w2 = e1_w1[128 + kf], w3 = e1_w1[192 + kf];
    float bb = e1_b1[kf];
    for (int e = eh * 64; e < eh * 64 + 64; ++e){
      float s = fmaf(eas[e*4+0], w0, fmaf(eas[e*4+1], w1, fmaf(eas[e*4+2], w2, fmaf(eas[e*4+3], w3, bb))));
      F1s[e * 66 + kf] = f2bf(fmaxf(s, 0.f));
    }
  }
  __syncthreads();

  const int w = tid >> 6, l = tid & 63, lm = l & 15, lg = l >> 4;
  int eloc[4], edst[4];
  float xs[4][4];
  #pragma unroll
  for (int et = 0; et < 4; ++et){
    eloc[et] = w * 64 + et * 16 + lm;
    int e = eblk + eloc[et];
    int s = ei[e];
    edst[et] = ei[N_EDGES + e];
    float4 xv = *(const float4*)(x + s * 4);
    xs[et][0] = xv.x; xs[et][1] = xv.y; xs[et][2] = xv.z; xs[et][3] = xv.w;
  }
  f32x4 acc[4][4];
  #pragma unroll
  for (int ot = 0; ot < 4; ++ot)
    #pragma unroll
    for (int et = 0; et < 4; ++et)
      acc[ot][et] = (f32x4){0.f, 0.f, 0.f, 0.f};

  #pragma unroll
  for (int cs = 0; cs < 9; ++cs){
    const int kb = cs * 32 + lg * 8;
    s16x8 a[4];
    #pragma unroll
    for (int ot = 0; ot < 4; ++ot){
      int r = ot * 16 + lm;
      a[ot] = *(const s16x8*)&T1s[r * 320 + (kb ^ ((r & 7) << 3))];
    }
    s16x8 b[4];
    #pragma unroll
    for (int et = 0; et < 4; ++et){
      float v[8];
      if (cs < 8){
        int kf0 = kb >> 2;
        float fa = bf2f(F1s[eloc[et] * 66 + kf0]);
        float fb = bf2f(F1s[eloc[et] * 66 + kf0 + 1]);
        #pragma unroll
        for (int j = 0; j < 8; ++j) v[j] = (j < 4 ? fa : fb) * xs[et][j & 3];
      } else { // bias K-step: A holds e1_b2 in cols 256..259, zeros beyond
        #pragma unroll
        for (int j = 0; j < 8; ++j) v[j] = xs[et][j & 3];
      }
      s16x8 bb;
      #pragma unroll
      for (int j = 0; j < 8; ++j) bb[j] = (short)f2bf(v[j]);
      b[et] = bb;
    }
    #pragma unroll
    for (int ot = 0; ot < 4; ++ot)
      #pragma unroll
      for (int et = 0; et < 4; ++et)
        acc[ot][et] = __builtin_amdgcn_mfma_f32_16x16x32_bf16(a[ot], b[et], acc[ot][et], 0, 0, 0);
  }
  #pragma unroll
  for (int et = 0; et < 4; ++et){
    float* base = agg + edst[et] * 64;
    #pragma unroll
    for (int ot = 0; ot < 4; ++ot)
      #pragma unroll
      for (int r = 0; r < 4; ++r)
        atomicAdd(base + ot * 16 + lg * 4 + r, acc[ot][et][r]);
  }
}

// ---------------- node update 1: mean-agg + x@root1 + bias, relu, LN -> h1 (f32 + bf16) ----------------
__global__ void k_node1(const float* __restrict__ x, const float* __restrict__ root1,
                        const float* __restrict__ bias1, const float* __restrict__ lng,
                        const float* __restrict__ lnb, const float* __restrict__ cnt,
                        float* __restrict__ agg, float* __restrict__ h1,
                        unsigned short* __restrict__ h1b)
{
  int gidx = blockIdx.x * 256 + threadIdx.x;
  int n = gidx >> 6, o = gidx & 63;
  float inv = 1.f / fmaxf(cnt[n], 1.f);
  float v = agg[gidx] * inv;
  float4 xv = *(const float4*)(x + n * 4);
  v = fmaf(xv.x, root1[o], v);
  v = fmaf(xv.y, root1[64 + o], v);
  v = fmaf(xv.z, root1[128 + o], v);
  v = fmaf(xv.w, root1[192 + o], v);
  v = fmaxf(v + bias1[o], 0.f);
  float m = v;
  #pragma unroll
  for (int s = 32; s > 0; s >>= 1) m += __shfl_xor(m, s);
  m *= (1.f / 64.f);
  float d = v - m;
  float var = d * d;
  #pragma unroll
  for (int s = 32; s > 0; s >>= 1) var += __shfl_xor(var, s);
  var *= (1.f / 64.f);
  float out = d * rsqrtf(var + 1e-5f) * lng[o] + lnb[o];
  h1[gidx] = out;
  h1b[gidx] = f2bf(out);
  agg[gidx] = 0.f;   // ready for layer-2 scatter
}

// ---------------- layer-2 edge messages: per-kf K=64 MFMA, f2-scaled accumulate ----------------
__device__ __forceinline__ void loada2(s16x8 (&dst)[4][2], const unsigned short* __restrict__ W2t,
                                       int kf, int lm, int lg)
{
  const s16x8* wp = (const s16x8*)(W2t + kf * 4096);
  #pragma unroll
  for (int ot = 0; ot < 4; ++ot){
    int rowo = ot * 16 + lm;
    dst[ot][0] = wp[rowo * 8 + lg];
    dst[ot][1] = wp[rowo * 8 + 4 + lg];
  }
}

__device__ __forceinline__ void comp2(const s16x8 (&a)[4][2], const s16x8 (&bh)[4][2],
                                      const unsigned short* F2s, const int (&eloc)[4],
                                      int kf, f32x4 (&acc)[4][4])
{
  float f2v[4];
  #pragma unroll
  for (int et = 0; et < 4; ++et) f2v[et] = bf2f(F2s[eloc[et] * 132 + kf]);
  #pragma unroll
  for (int ot = 0; ot < 4; ++ot){
    #pragma unroll
    for (int et = 0; et < 4; ++et){
      f32x4 g = (f32x4){0.f, 0.f, 0.f, 0.f};
      g = __builtin_amdgcn_mfma_f32_16x16x32_bf16(a[ot][0], bh[et][0], g, 0, 0, 0);
      g = __builtin_amdgcn_mfma_f32_16x16x32_bf16(a[ot][1], bh[et][1], g, 0, 0, 0);
      #pragma unroll
      for (int r = 0; r < 4; ++r) acc[ot][et][r] = fmaf(f2v[et], g[r], acc[ot][et][r]);
    }
  }
}

__launch_bounds__(128, 2)
__global__ void k_msg2(const float* __restrict__ ea, const int* __restrict__ ei,
                       const float* __restrict__ e2_w1, const float* __restrict__ e2_b1,
                       const unsigned short* __restrict__ h1b,
                       const unsigned short* __restrict__ W2t,
                       float* __restrict__ agg)
{
  __shared__ float eas[64 * 4];
  __shared__ unsigned short F2s[64 * 132];   // [edge][kf 0..128], col 128 == 1.0 (bias slot)
  const int tid = threadIdx.x;
  const int eblk = blockIdx.x * 64;
  if (tid < 64) ((float4*)eas)[tid] = ((const float4*)ea)[eblk + tid];
  __syncthreads();
  {
    int kf = tid;
    float w0 = e2_w1[kf], w1 = e2_w1[128 + kf], w2 = e2_w1[256 + kf], w3 = e2_w1[384 + kf];
    float bb = e2_b1[kf];
    for (int e = 0; e < 64; ++e){
      float s = fmaf(eas[e*4+0], w0, fmaf(eas[e*4+1], w1, fmaf(eas[e*4+2], w2, fmaf(eas[e*4+3], w3, bb))));
      F2s[e * 132 + kf] = f2bf(fmaxf(s, 0.f));
    }
    if (tid < 64) F2s[tid * 132 + 128] = 0x3F80;  // 1.0f in bf16
  }
  __syncthreads();

  const int w = tid >> 6, l = tid & 63, lm = l & 15, lg = l >> 4;
  int eloc[4], edst[4];
  s16x8 bh[4][2];
  #pragma unroll
  for (int et = 0; et < 4; ++et){
    eloc[et] = et * 16 + lm;
    int e = eblk + eloc[et];
    int s = ei[e];
    edst[et] = ei[N_EDGES + e];
    const s16x8* hp = (const s16x8*)(h1b + s * 64);
    bh[et][0] = hp[lg];
    bh[et][1] = hp[4 + lg];
  }
  f32x4 acc[4][4];
  #pragma unroll
  for (int ot = 0; ot < 4; ++ot)
    #pragma unroll
    for (int et = 0; et < 4; ++et)
      acc[ot][et] = (f32x4){0.f, 0.f, 0.f, 0.f};

  const int kf0 = (w == 0) ? 0 : 64;
  const int kfe = (w == 0) ? 64 : 129;
  s16x8 aA[4][2], aB[4][2];
  int kf = kf0;
  loada2(aA, W2t, kf, lm, lg);
  while (kf < kfe){
    int kn = (kf + 1 < kfe) ? kf + 1 : kf;
    loada2(aB, W2t, kn, lm, lg);
    comp2(aA, bh, F2s, eloc, kf, acc);
    ++kf;
    if (kf >= kfe) break;
    kn = (kf + 1 < kfe) ? kf + 1 : kf;
    loada2(aA, W2t, kn, lm, lg);
    comp2(aB, bh, F2s, eloc, kf, acc);
    ++kf;
  }
  #pragma unroll
  for (int et = 0; et < 4; ++et){
    float* base = agg + edst[et] * 64;
    #pragma unroll
    for (int ot = 0; ot < 4; ++ot)
      #pragma unroll
      for (int r = 0; r < 4; ++r)
        atomicAdd(base + ot * 16 + lg * 4 + r, acc[ot][et][r]);
  }
}

// ---------------- node update 2: mean-agg + h1@root2 + bias, relu, LN -> h2 (into agg) ----------------
__global__ void k_node2(const float* __restrict__ h1, const float* __restrict__ root2,
                        const float* __restrict__ bias2, const float* __restrict__ lng,
                        const float* __restrict__ lnb, const float* __restrict__ cnt,
                        float* __restrict__ agg)
{
  int gidx = blockIdx.x * 256 + threadIdx.x;
  int n = gidx >> 6, o = gidx & 63;
  float inv = 1.f / fmaxf(cnt[n], 1.f);
  float v = agg[gidx] * inv;
  const float* hr = h1 + n * 64;
  #pragma unroll 8
  for (int i = 0; i < 64; ++i) v = fmaf(hr[i], root2[i * 64 + o], v);
  v = fmaxf(v + bias2[o], 0.f);
  float m = v;
  #pragma unroll
  for (int s = 32; s > 0; s >>= 1) m += __shfl_xor(m, s);
  m *= (1.f / 64.f);
  float d = v - m;
  float var = d * d;
  #pragma unroll
  for (int s = 32; s > 0; s >>= 1) var += __shfl_xor(var, s);
  var *= (1.f / 64.f);
  float out = d * rsqrtf(var + 1e-5f) * lng[o] + lnb[o];
  agg[gidx] = out;
}

// ---------------- global mean pool ----------------
__global__ void k_pool(const float* __restrict__ h2, float* __restrict__ pool){
  int gidx = blockIdx.x * 256 + threadIdx.x;   // grid 128 x 256 -> 512 groups x 64 o
  int grp = gidx >> 6, o = gidx & 63;
  float s = 0.f;
  for (int n = grp; n < N_NODES; n += 512) s += h2[n * 64 + o];
  atomicAdd(pool + o, s);
}

__global__ void k_out(const float* __restrict__ pool, float* __restrict__ out){
  int o = threadIdx.x;
  if (o < 64) out[o] = pool[o] * (1.f / 32768.f);
}

extern "C" void kernel_launch(void* const* d_in, const int* in_sizes, int n_in,
                              void* d_out, int out_size, void* d_ws, size_t ws_size,
                              hipStream_t stream)
{
  const float* x      = (const float*)d_in[0];
  const float* ea     = (const float*)d_in[1];
  const int*   ei     = (const int*)  d_in[2];
  const float* e1_w1  = (const float*)d_in[4];
  const float* e1_b1  = (const float*)d_in[5];
  const float* e1_w2  = (const float*)d_in[6];
  const float* e1_b2  = (const float*)d_in[7];
  const float* root1  = (const float*)d_in[8];
  const float* bias1  = (const float*)d_in[9];
  const float* ln1g   = (const float*)d_in[10];
  const float* ln1b   = (const float*)d_in[11];
  const float* e2_w1  = (const float*)d_in[12];
  const float* e2_b1  = (const float*)d_in[13];
  const float* e2_w2  = (const float*)d_in[14];
  const float* e2_b2  = (const float*)d_in[15];
  const float* root2  = (const float*)d_in[16];
  const float* bias2  = (const float*)d_in[17];
  const float* ln2g   = (const float*)d_in[18];
  const float* ln2b   = (const float*)d_in[19];

  char* w = (char*)d_ws;
  float*          agg  = (float*)(w);                       // 8,388,608 B
  float*          cnt  = (float*)(w + 8388608);             //   131,072 B
  float*          pool = (float*)(w + 8519680);             //       256 B
  float*          h1   = (float*)(w + 8519936);             // 8,388,608 B
  unsigned short* h1b  = (unsigned short*)(w + 16908544);   // 4,194,304 B
  unsigned short* W2t  = (unsigned short*)(w + 21102848);   // 1,056,768 B
  unsigned short* T1x  = (unsigned short*)(w + 22159616);   //    36,864 B

  k_zero<<<8321, 256, 0, stream>>>((float*)w, 2129984);     // agg + cnt + pool
  k_prep<<<2136, 256, 0, stream>>>(e2_w2, e2_b2, e1_w2, e1_b2, W2t, T1x);
  k_cnt <<<256, 256, 0, stream>>>(ei, cnt);
  k_msg1<<<512, 128, 0, stream>>>(x, ea, ei, e1_w1, e1_b1, T1x, agg);
  k_node1<<<8192, 256, 0, stream>>>(x, root1, bias1, ln1g, ln1b, cnt, agg, h1, h1b);
  k_msg2<<<1024, 128, 0, stream>>>(ea, ei, e2_w1, e2_b1, h1b, W2t, agg);
  k_node2<<<8192, 256, 0, stream>>>(h1, root2, bias2, ln2g, ln2b, cnt, agg);
  k_pool<<<128, 256, 0, stream>>>(agg, pool);
  k_out <<<1, 64, 0, stream>>>(pool, (float*)d_out);
}

// Round 2
// 229.561 us; speedup vs baseline: 1.6465x; 1.6465x over previous
//
#include <hip/hip_runtime.h>

#define N_NODES 32768
#define N_EDGES 65536

typedef float f32x4 __attribute__((ext_vector_type(4)));
typedef short s16x8 __attribute__((ext_vector_type(8)));

__device__ __forceinline__ unsigned short f2bf(float f){
  unsigned u = __float_as_uint(f);
  u += 0x7FFFu + ((u >> 16) & 1u);          // round-to-nearest-even
  return (unsigned short)(u >> 16);
}
__device__ __forceinline__ float bf2f(unsigned short b){
  return __uint_as_float(((unsigned)b) << 16);
}

// ---------------- zero workspace (agg | cnt | pool contiguous) ----------------
__global__ void k_zero(float* __restrict__ p, int n){
  int i = blockIdx.x * 256 + threadIdx.x;
  if (i < n) p[i] = 0.f;
}

// ---- prep: W2f = e2_w2/e2_b2 in MFMA A-fragment order [kf 0..128][ot][half][lane][8]
// ----       T1g = e1_w2 in A-fragment order [i 0..3][ot][half][lane][8]
__global__ void k_prep(const float* __restrict__ e2_w2, const float* __restrict__ e2_b2,
                       const float* __restrict__ e1_w2,
                       unsigned short* __restrict__ W2f, unsigned short* __restrict__ T1g){
  int idx = blockIdx.x * 256 + threadIdx.x;
  if (idx < 129 * 4096){
    int j = idx & 7, l = (idx >> 3) & 63, half = (idx >> 9) & 1, ot = (idx >> 10) & 3, kf = idx >> 12;
    int i = half * 32 + ((l >> 4) << 3) + j;
    int o = ot * 16 + (l & 15);
    float v = (kf < 128) ? e2_w2[kf * 4096 + i * 64 + o] : e2_b2[i * 64 + o];
    W2f[idx] = f2bf(v);
  } else if (idx < 129 * 4096 + 16384){
    int t = idx - 129 * 4096;
    int j = t & 7, l = (t >> 3) & 63, half = (t >> 9) & 1, ot = (t >> 10) & 3, i = t >> 12;
    int kf = half * 32 + ((l >> 4) << 3) + j;
    int o = ot * 16 + (l & 15);
    T1g[t] = f2bf(e1_w2[kf * 256 + i * 64 + o]);
  }
}

// ---------------- degree counts ----------------
__global__ void k_cnt(const int* __restrict__ ei, float* __restrict__ cnt){
  int i = blockIdx.x * 256 + threadIdx.x;
  if (i < N_EDGES) atomicAdd(cnt + ei[N_EDGES + i], 1.f);
}

// ---------------- layer-1 edge messages: 4 waves, ot-split, 4 i-GEMMs ----------------
__launch_bounds__(256, 4)
__global__ void k_msg1(const float* __restrict__ x, const float* __restrict__ ea,
                       const int* __restrict__ ei,
                       const float* __restrict__ e1_w1, const float* __restrict__ e1_b1,
                       const float* __restrict__ e1_b2,
                       const unsigned short* __restrict__ T1g,
                       float* __restrict__ agg)
{
  __shared__ float eas[64 * 4];
  __shared__ unsigned short F1f[8 * 64 * 8];   // B-fragment layout [(et*2+half)][lane][8]
  const int tid = threadIdx.x;
  const int eblk = blockIdx.x * 64;

  if (tid < 64) ((float4*)eas)[tid] = ((const float4*)ea)[eblk + tid];
  __syncthreads();
  { // F1 = relu(ea @ e1_w1 + b1), stored directly in B-fragment order
    int kf = tid & 63, eh = tid >> 6;
    float w0 = e1_w1[kf], w1 = e1_w1[64 + kf], w2 = e1_w1[128 + kf], w3 = e1_w1[192 + kf];
    float bb = e1_b1[kf];
    int half = kf >> 5, hi = (kf >> 3) & 3, j = kf & 7;
    for (int e = eh * 16; e < eh * 16 + 16; ++e){
      float s = fmaf(eas[e*4+0], w0, fmaf(eas[e*4+1], w1, fmaf(eas[e*4+2], w2, fmaf(eas[e*4+3], w3, bb))));
      F1f[(((e >> 4) * 2 + half) * 64 + hi * 16 + (e & 15)) * 8 + j] = f2bf(fmaxf(s, 0.f));
    }
  }
  __syncthreads();

  const int l = tid & 63, lm = l & 15, lg = l >> 4;
  const int ot = tid >> 6;
  int edst[4];
  float xs[4][4];
  s16x8 bf[4][2];
  #pragma unroll
  for (int et = 0; et < 4; ++et){
    int e = eblk + et * 16 + lm;
    int s = ei[e];
    edst[et] = ei[N_EDGES + e];
    float4 xv = *(const float4*)(x + s * 4);
    xs[et][0] = xv.x; xs[et][1] = xv.y; xs[et][2] = xv.z; xs[et][3] = xv.w;
    bf[et][0] = ((const s16x8*)F1f)[(et * 2 + 0) * 64 + l];
    bf[et][1] = ((const s16x8*)F1f)[(et * 2 + 1) * 64 + l];
  }
  f32x4 acc[4];
  #pragma unroll
  for (int et = 0; et < 4; ++et) acc[et] = (f32x4){0.f, 0.f, 0.f, 0.f};

  #pragma unroll
  for (int i = 0; i < 4; ++i){
    const s16x8* p = (const s16x8*)(T1g + (i * 4 + ot) * 1024);
    s16x8 a0 = p[l], a1 = p[64 + l];
    #pragma unroll
    for (int et = 0; et < 4; ++et){
      f32x4 g = (f32x4){0.f, 0.f, 0.f, 0.f};
      g = __builtin_amdgcn_mfma_f32_16x16x32_bf16(a0, bf[et][0], g, 0, 0, 0);
      g = __builtin_amdgcn_mfma_f32_16x16x32_bf16(a1, bf[et][1], g, 0, 0, 0);
      #pragma unroll
      for (int r = 0; r < 4; ++r) acc[et][r] = fmaf(xs[et][i], g[r], acc[et][r]);
    }
  }
  // bias fold: acc[et][r] += sum_i xs[et][i] * e1_b2[i*64 + o],  o = ot*16 + lg*4 + r
  float b2v[4][4];
  #pragma unroll
  for (int i = 0; i < 4; ++i)
    #pragma unroll
    for (int r = 0; r < 4; ++r) b2v[i][r] = e1_b2[i * 64 + ot * 16 + lg * 4 + r];
  #pragma unroll
  for (int et = 0; et < 4; ++et)
    #pragma unroll
    for (int r = 0; r < 4; ++r)
      #pragma unroll
      for (int i = 0; i < 4; ++i) acc[et][r] = fmaf(xs[et][i], b2v[i][r], acc[et][r]);

  #pragma unroll
  for (int et = 0; et < 4; ++et){
    float* base = agg + edst[et] * 64 + ot * 16 + lg * 4;
    #pragma unroll
    for (int r = 0; r < 4; ++r) atomicAdd(base + r, acc[et][r]);
  }
}

// ---------------- node update 1 ----------------
__global__ void k_node1(const float* __restrict__ x, const float* __restrict__ root1,
                        const float* __restrict__ bias1, const float* __restrict__ lng,
                        const float* __restrict__ lnb, const float* __restrict__ cnt,
                        float* __restrict__ agg, float* __restrict__ h1,
                        unsigned short* __restrict__ h1b)
{
  int gidx = blockIdx.x * 256 + threadIdx.x;
  int n = gidx >> 6, o = gidx & 63;
  float inv = 1.f / fmaxf(cnt[n], 1.f);
  float v = agg[gidx] * inv;
  float4 xv = *(const float4*)(x + n * 4);
  v = fmaf(xv.x, root1[o], v);
  v = fmaf(xv.y, root1[64 + o], v);
  v = fmaf(xv.z, root1[128 + o], v);
  v = fmaf(xv.w, root1[192 + o], v);
  v = fmaxf(v + bias1[o], 0.f);
  float m = v;
  #pragma unroll
  for (int s = 32; s > 0; s >>= 1) m += __shfl_xor(m, s);
  m *= (1.f / 64.f);
  float d = v - m;
  float var = d * d;
  #pragma unroll
  for (int s = 32; s > 0; s >>= 1) var += __shfl_xor(var, s);
  var *= (1.f / 64.f);
  float out = d * rsqrtf(var + 1e-5f) * lng[o] + lnb[o];
  h1[gidx] = out;
  h1b[gidx] = f2bf(out);
  agg[gidx] = 0.f;   // ready for layer-2 scatter
}

// ---------------- layer-2 edge messages: 8 waves (ot x edge-half), full K per wave ----------------
__launch_bounds__(512, 4)
__global__ void k_msg2(const float* __restrict__ ea, const int* __restrict__ ei,
                       const float* __restrict__ e2_w1, const float* __restrict__ e2_b1,
                       const unsigned short* __restrict__ h1b,
                       const unsigned short* __restrict__ W2f,
                       float* __restrict__ agg)
{
  __shared__ float eas[128 * 4];
  __shared__ unsigned short F2s[128 * 132];   // [edge][kf 0..128], col 128 == 1.0 (bias slot)
  const int tid = threadIdx.x;
  const int eblk = blockIdx.x * 128;
  if (tid < 128) ((float4*)eas)[tid] = ((const float4*)ea)[eblk + tid];
  __syncthreads();
  {
    int kf = tid & 127, q = tid >> 7;
    float w0 = e2_w1[kf], w1 = e2_w1[128 + kf], w2 = e2_w1[256 + kf], w3 = e2_w1[384 + kf];
    float bb = e2_b1[kf];
    for (int e = q * 32; e < q * 32 + 32; ++e){
      float s = fmaf(eas[e*4+0], w0, fmaf(eas[e*4+1], w1, fmaf(eas[e*4+2], w2, fmaf(eas[e*4+3], w3, bb))));
      F2s[e * 132 + kf] = f2bf(fmaxf(s, 0.f));
    }
    if (tid < 128) F2s[tid * 132 + 128] = 0x3F80;  // 1.0f bf16
  }
  __syncthreads();

  const int w = tid >> 6, l = tid & 63, lm = l & 15, lg = l >> 4;
  const int ot = w >> 1, eh = w & 1;
  int eloc[4], edst[4];
  s16x8 bh[4][2];
  #pragma unroll
  for (int et = 0; et < 4; ++et){
    eloc[et] = eh * 64 + et * 16 + lm;
    int e = eblk + eloc[et];
    int s = ei[e];
    edst[et] = ei[N_EDGES + e];
    const s16x8* hp = (const s16x8*)(h1b + s * 64);
    bh[et][0] = hp[lg];
    bh[et][1] = hp[4 + lg];
  }
  f32x4 acc[4];
  #pragma unroll
  for (int et = 0; et < 4; ++et) acc[et] = (f32x4){0.f, 0.f, 0.f, 0.f};

  const unsigned short* wbase = W2f + ot * 1024;
  s16x8 a0[2], a1[2];
  #define LOADA(A, KF) { const s16x8* p = (const s16x8*)(wbase + (KF) * 4096); A[0] = p[l]; A[1] = p[64 + l]; }
  #define STEP(A, KF) { \
    float f2v[4]; \
    _Pragma("unroll") \
    for (int et = 0; et < 4; ++et) f2v[et] = bf2f(F2s[eloc[et] * 132 + (KF)]); \
    _Pragma("unroll") \
    for (int et = 0; et < 4; ++et){ \
      f32x4 g = (f32x4){0.f, 0.f, 0.f, 0.f}; \
      g = __builtin_amdgcn_mfma_f32_16x16x32_bf16(A[0], bh[et][0], g, 0, 0, 0); \
      g = __builtin_amdgcn_mfma_f32_16x16x32_bf16(A[1], bh[et][1], g, 0, 0, 0); \
      _Pragma("unroll") \
      for (int r = 0; r < 4; ++r) acc[et][r] = fmaf(f2v[et], g[r], acc[et][r]); \
    } }

  LOADA(a0, 0)
  #pragma unroll 1
  for (int kf = 0; kf < 128; kf += 2){
    LOADA(a1, kf + 1)
    STEP(a0, kf)
    LOADA(a0, kf + 2)          // kf+2 <= 128 (bias slab) always valid
    STEP(a1, kf + 1)
  }
  STEP(a0, 128)
  #undef LOADA
  #undef STEP

  #pragma unroll
  for (int et = 0; et < 4; ++et){
    float* base = agg + edst[et] * 64 + ot * 16 + lg * 4;
    #pragma unroll
    for (int r = 0; r < 4; ++r) atomicAdd(base + r, acc[et][r]);
  }
}

// ---------------- node update 2 ----------------
__global__ void k_node2(const float* __restrict__ h1, const float* __restrict__ root2,
                        const float* __restrict__ bias2, const float* __restrict__ lng,
                        const float* __restrict__ lnb, const float* __restrict__ cnt,
                        float* __restrict__ agg)
{
  int gidx = blockIdx.x * 256 + threadIdx.x;
  int n = gidx >> 6, o = gidx & 63;
  float inv = 1.f / fmaxf(cnt[n], 1.f);
  float v = agg[gidx] * inv;
  const float* hr = h1 + n * 64;
  #pragma unroll 8
  for (int i = 0; i < 64; ++i) v = fmaf(hr[i], root2[i * 64 + o], v);
  v = fmaxf(v + bias2[o], 0.f);
  float m = v;
  #pragma unroll
  for (int s = 32; s > 0; s >>= 1) m += __shfl_xor(m, s);
  m *= (1.f / 64.f);
  float d = v - m;
  float var = d * d;
  #pragma unroll
  for (int s = 32; s > 0; s >>= 1) var += __shfl_xor(var, s);
  var *= (1.f / 64.f);
  float out = d * rsqrtf(var + 1e-5f) * lng[o] + lnb[o];
  agg[gidx] = out;
}

// ---------------- global mean pool ----------------
__global__ void k_pool(const float* __restrict__ h2, float* __restrict__ pool){
  int gidx = blockIdx.x * 256 + threadIdx.x;   // 512 groups x 64 o
  int grp = gidx >> 6, o = gidx & 63;
  float s = 0.f;
  for (int n = grp; n < N_NODES; n += 512) s += h2[n * 64 + o];
  atomicAdd(pool + o, s);
}

__global__ void k_out(const float* __restrict__ pool, float* __restrict__ out){
  int o = threadIdx.x;
  if (o < 64) out[o] = pool[o] * (1.f / 32768.f);
}

extern "C" void kernel_launch(void* const* d_in, const int* in_sizes, int n_in,
                              void* d_out, int out_size, void* d_ws, size_t ws_size,
                              hipStream_t stream)
{
  const float* x      = (const float*)d_in[0];
  const float* ea     = (const float*)d_in[1];
  const int*   ei     = (const int*)  d_in[2];
  const float* e1_w1  = (const float*)d_in[4];
  const float* e1_b1  = (const float*)d_in[5];
  const float* e1_w2  = (const float*)d_in[6];
  const float* e1_b2  = (const float*)d_in[7];
  const float* root1  = (const float*)d_in[8];
  const float* bias1  = (const float*)d_in[9];
  const float* ln1g   = (const float*)d_in[10];
  const float* ln1b   = (const float*)d_in[11];
  const float* e2_w1  = (const float*)d_in[12];
  const float* e2_b1  = (const float*)d_in[13];
  const float* e2_w2  = (const float*)d_in[14];
  const float* e2_b2  = (const float*)d_in[15];
  const float* root2  = (const float*)d_in[16];
  const float* bias2  = (const float*)d_in[17];
  const float* ln2g   = (const float*)d_in[18];
  const float* ln2b   = (const float*)d_in[19];

  char* w = (char*)d_ws;
  float*          agg  = (float*)(w);                       // 8,388,608 B
  float*          cnt  = (float*)(w + 8388608);             //   131,072 B
  float*          pool = (float*)(w + 8519680);             //       256 B
  float*          h1   = (float*)(w + 8519936);             // 8,388,608 B
  unsigned short* h1b  = (unsigned short*)(w + 16908544);   // 4,194,304 B
  unsigned short* W2f  = (unsigned short*)(w + 21102848);   // 1,056,768 B
  unsigned short* T1g  = (unsigned short*)(w + 22159616);   //    32,768 B

  k_zero<<<8321, 256, 0, stream>>>((float*)w, 2129984);     // agg + cnt + pool
  k_prep<<<2128, 256, 0, stream>>>(e2_w2, e2_b2, e1_w2, W2f, T1g);
  k_cnt <<<256, 256, 0, stream>>>(ei, cnt);
  k_msg1<<<1024, 256, 0, stream>>>(x, ea, ei, e1_w1, e1_b1, e1_b2, T1g, agg);
  k_node1<<<8192, 256, 0, stream>>>(x, root1, bias1, ln1g, ln1b, cnt, agg, h1, h1b);
  k_msg2<<<512, 512, 0, stream>>>(ea, ei, e2_w1, e2_b1, h1b, W2f, agg);
  k_node2<<<8192, 256, 0, stream>>>(h1, root2, bias2, ln2g, ln2b, cnt, agg);
  k_pool<<<128, 256, 0, stream>>>(agg, pool);
  k_out <<<1, 64, 0, stream>>>(pool, (float*)d_out);
}